// Round 1
// 465.587 us; speedup vs baseline: 2.7288x; 2.7288x over previous
//
#include <hip/hip_runtime.h>
#include <math.h>

typedef __attribute__((ext_vector_type(8))) short short8;
typedef __attribute__((ext_vector_type(4))) float floatx4;

__device__ __forceinline__ float bits2f(short u) {
  unsigned int x = ((unsigned int)(unsigned short)u) << 16;
  return __builtin_bit_cast(float, x);
}
__device__ __forceinline__ short f2bits(float f) {
  unsigned int x = __builtin_bit_cast(unsigned int, f);
  x += 0x7FFFu + ((x >> 16) & 1u);   // RNE
  return (short)(x >> 16);
}

__device__ __forceinline__ void gload_lds16(const short* g, short* l) {
  __builtin_amdgcn_global_load_lds((const __attribute__((address_space(1))) void*)g,
                                   (__attribute__((address_space(3))) void*)l, 16, 0, 0);
}

// ---------------------------------------------------------------------------
// f32 -> bf16 (RNE), 8 elems/thread, grid-stride. n8 = n_elems/8.
// ---------------------------------------------------------------------------
__global__ __launch_bounds__(256) void cvt_bf16(const float* __restrict__ in,
                                                short* __restrict__ out, long n8) {
  long i = (long)blockIdx.x * 256 + threadIdx.x;
  const long stride = (long)gridDim.x * 256;
  for (; i < n8; i += stride) {
    const floatx4* p = (const floatx4*)(in + i * 8);
    floatx4 v0 = p[0], v1 = p[1];
    short8 o;
#pragma unroll
    for (int e = 0; e < 4; e++) { o[e] = f2bits(v0[e]); o[e + 4] = f2bits(v1[e]); }
    *(short8*)(out + i * 8) = o;
  }
}

// ---------------------------------------------------------------------------
// C[m][n] = sum_k A[m][k]*B[n][k], bf16 A/B (K-contiguous), fp32 acc.
// m97 structure: 128x128 block tile, BK=32, 4 waves (2x2), global_load_lds
// width-16 staging, ds_read_b128 fragments, 16 MFMA/K-step.
// Requires M%128==0, N%128==0, K%32==0, gridDim.x%8==0 (XCD swizzle).
// ---------------------------------------------------------------------------
template <bool COUT_F32>
__global__ __launch_bounds__(256) void gemm_lds(const short* __restrict__ A,
                                                const short* __restrict__ B,
                                                void* __restrict__ C,
                                                int M, int N, int K) {
  __shared__ __attribute__((aligned(16))) short sA[128 * 32];
  __shared__ __attribute__((aligned(16))) short sB[128 * 32];

  const int tid  = threadIdx.x;
  const int lane = tid & 63;
  const int wave = tid >> 6;
  const int frow = lane & 15;
  const int quad = lane >> 4;

  // bijective XCD-aware swizzle (gridDim.x % 8 == 0)
  const int nwg = gridDim.x;
  const int cpx = nwg >> 3;
  const int bid = blockIdx.x;
  const int swz = (bid & 7) * cpx + (bid >> 3);
  const int nbx = N >> 7;
  const int bx  = swz % nbx;
  const int by  = swz / nbx;

  const long m0 = (long)by * 128;
  const long n0 = (long)bx * 128;

  // staging: 512 chunks of 16B per tile; thread owns chunks c0 and c0+256.
  // chunk c -> row c>>2, k-offset (c&3)*8 elems.
  const int  c0    = tid;
  const long aoff  = (m0 + (c0 >> 2)) * (long)K + (c0 & 3) * 8;
  const long boff  = (n0 + (c0 >> 2)) * (long)K + (c0 & 3) * 8;
  const long rstep = 64L * K;   // +256 chunks = +64 rows

  floatx4 acc[4][4];
#pragma unroll
  for (int i = 0; i < 4; i++)
#pragma unroll
    for (int j = 0; j < 4; j++) acc[i][j] = (floatx4){0.f, 0.f, 0.f, 0.f};

  const int arow = (wave >> 1) * 64 + frow;   // local A row (plus mi*16)
  const int brow = (wave &  1) * 64 + frow;   // local B row (plus ni*16)

  for (int k0 = 0; k0 < K; k0 += 32) {
    __syncthreads();   // previous iter's LDS reads done
    gload_lds16(A + aoff + k0,         sA + c0 * 8);
    gload_lds16(A + aoff + rstep + k0, sA + c0 * 8 + 2048);
    gload_lds16(B + boff + k0,         sB + c0 * 8);
    gload_lds16(B + boff + rstep + k0, sB + c0 * 8 + 2048);
    __syncthreads();   // staged data visible (compiler drains vmcnt)

    short8 a[4], b[4];
#pragma unroll
    for (int i = 0; i < 4; i++) a[i] = *(const short8*)&sA[(arow + i * 16) * 32 + quad * 8];
#pragma unroll
    for (int i = 0; i < 4; i++) b[i] = *(const short8*)&sB[(brow + i * 16) * 32 + quad * 8];
#pragma unroll
    for (int mi = 0; mi < 4; mi++)
#pragma unroll
      for (int ni = 0; ni < 4; ni++)
        acc[mi][ni] = __builtin_amdgcn_mfma_f32_16x16x32_bf16(a[mi], b[ni], acc[mi][ni], 0, 0, 0);
  }

  const long mrow0 = m0 + (wave >> 1) * 64;
  const long ncol0 = n0 + (wave &  1) * 64;
#pragma unroll
  for (int mi = 0; mi < 4; mi++)
#pragma unroll
    for (int ni = 0; ni < 4; ni++) {
      long row0 = mrow0 + mi * 16 + quad * 4;   // C/D: col=lane&15, row=quad*4+r
      long col  = ncol0 + ni * 16 + frow;
#pragma unroll
      for (int r = 0; r < 4; r++) {
        if constexpr (COUT_F32)
          ((float*)C)[(row0 + r) * (long)N + col] = acc[mi][ni][r];
        else
          ((short*)C)[(row0 + r) * (long)N + col] = f2bits(acc[mi][ni][r]);
      }
    }
}

// ---------------------------------------------------------------------------
// Scalar attention, vectorized loads: 1 wave per (head, chunk, batch);
// thread = query position. qkv bf16 in, y bf16 out.
// ---------------------------------------------------------------------------
__global__ __launch_bounds__(64) void attn_simple(const short* __restrict__ qkv,
                                                  short* __restrict__ y) {
  const int t = threadIdx.x;       // query position within chunk (0..63)
  const int h = blockIdx.x;        // head
  const int chunk = blockIdx.y;
  const int b = blockIdx.z;

  __shared__ __attribute__((aligned(16))) float kk[64][68];  // roped k rows
  __shared__ __attribute__((aligned(16))) float vv[64][68];  // raw v rows

  const long rowbase = (long)b * 4096 + (long)chunk * 64;
  const short* base = qkv + (rowbase + t) * 3072 + h * 64;

  // per-thread rope factors for position t
  float ct[32], st[32];
#pragma unroll
  for (int j = 0; j < 32; j++) {
    float inv = exp2f(-(float)j * 0.41524101186092030f);  // 10000^(-j/32)
    float ang = (float)t * inv;
    st[j] = sinf(ang);
    ct[j] = cosf(ang);
  }

  // q row -> regs (roped, f32)
  float q[64];
  {
    float raw[64];
#pragma unroll
    for (int i = 0; i < 8; i++) {
      short8 r = *(const short8*)(base + i * 8);
#pragma unroll
      for (int e = 0; e < 8; e++) raw[i * 8 + e] = bits2f(r[e]);
    }
#pragma unroll
    for (int c = 0; c < 32; c++) {
      q[c]      = raw[c] * ct[c] + raw[c + 32] * st[c];
      q[c + 32] = raw[c + 32] * ct[c] - raw[c] * st[c];
    }
  }
  // k row -> LDS (roped)
  {
    float raw[64];
#pragma unroll
    for (int i = 0; i < 8; i++) {
      short8 r = *(const short8*)(base + 1024 + i * 8);
#pragma unroll
      for (int e = 0; e < 8; e++) raw[i * 8 + e] = bits2f(r[e]);
    }
#pragma unroll
    for (int c = 0; c < 32; c++) {
      kk[t][c]      = raw[c] * ct[c] + raw[c + 32] * st[c];
      kk[t][c + 32] = raw[c + 32] * ct[c] - raw[c] * st[c];
    }
  }
  // v row -> LDS (raw)
#pragma unroll
  for (int i = 0; i < 8; i++) {
    short8 r = *(const short8*)(base + 2048 + i * 8);
#pragma unroll
    for (int e = 0; e < 8; e++) vv[t][i * 8 + e] = bits2f(r[e]);
  }

  __syncthreads();

  // scores (kk reads are lane-uniform -> LDS broadcast, conflict-free)
  float s[64];
  for (int j = 0; j < 64; j++) {
    floatx4 a4 = {0.f, 0.f, 0.f, 0.f};
#pragma unroll
    for (int d4 = 0; d4 < 16; d4++) {
      floatx4 kv = *(const floatx4*)&kk[j][d4 * 4];
#pragma unroll
      for (int e = 0; e < 4; e++) a4[e] += q[d4 * 4 + e] * kv[e];
    }
    s[j] = (a4[0] + a4[1] + a4[2] + a4[3]) * 0.125f;   // 1/sqrt(64)
  }

  // softmax (fully in-thread)
  float mx = -3.0e38f;
  for (int j = 0; j < 64; j++) mx = fmaxf(mx, s[j]);
  float sum = 0.f;
  for (int j = 0; j < 64; j++) { s[j] = __expf(s[j] - mx); sum += s[j]; }
  float isum = 1.0f / sum;

  // y row = p @ V
  floatx4 o[16];
#pragma unroll
  for (int d4 = 0; d4 < 16; d4++) o[d4] = (floatx4){0.f, 0.f, 0.f, 0.f};
  for (int j = 0; j < 64; j++) {
    float pj = s[j] * isum;
#pragma unroll
    for (int d4 = 0; d4 < 16; d4++) {
      floatx4 v4 = *(const floatx4*)&vv[j][d4 * 4];
#pragma unroll
      for (int e = 0; e < 4; e++) o[d4][e] += pj * v4[e];
    }
  }

  // write y row (bf16, vectorized)
  short* dst = y + (rowbase + t) * 1024 + h * 64;
#pragma unroll
  for (int i = 0; i < 8; i++) {
    short8 w;
#pragma unroll
    for (int e = 0; e < 8; e++) { int d = i * 8 + e; w[e] = f2bits(o[d >> 2][d & 3]); }
    *(short8*)(dst + i * 8) = w;
  }
}

// ---------------------------------------------------------------------------
extern "C" void kernel_launch(void* const* d_in, const int* in_sizes, int n_in,
                              void* d_out, int out_size, void* d_ws, size_t ws_size,
                              hipStream_t stream) {
  (void)in_sizes; (void)n_in; (void)out_size; (void)ws_size;
  const float* x      = (const float*)d_in[0];  // f32 (4,4096,1024)
  const float* w_attn = (const float*)d_in[1];  // f32 (3072,1024)
  const float* w_proj = (const float*)d_in[2];  // f32 (1024,1024)
  float* out = (float*)d_out;                   // f32 (4,4096,1024)

  // ws layout (128 MiB total, same as before):
  //   qkv: ws+0      .. 96 MiB   (bf16 16384x3072); later reused for w_proj bf16
  //   yb : ws+96MiB  .. 32 MiB   (bf16 16384x1024); first reused for w_attn bf16
  // xb (bf16 x, 32 MiB) lives in d_out — fully overwritten by the final GEMM.
  short* qkv = (short*)d_ws;
  short* yb  = qkv + (size_t)16384 * 3072;
  short* wab = yb;            // w_attn bf16 (6 MiB) — dead before attn writes yb
  short* wpb = qkv;           // w_proj bf16 (2 MiB) — written after attn reads qkv
  short* xb  = (short*)d_out; // x bf16 (32 MiB) — dead before gemm2 writes out

  cvt_bf16<<<dim3(2048), 256, 0, stream>>>(x,      xb,  (long)16384 * 1024 / 8);
  cvt_bf16<<<dim3(1024), 256, 0, stream>>>(w_attn, wab, (long)3072 * 1024 / 8);
  // qkv = x @ w_attn^T  (bf16 -> bf16)
  gemm_lds<false><<<dim3(3072), 256, 0, stream>>>(xb, wab, qkv, 16384, 3072, 1024);
  // chunked attention -> y (bf16)
  attn_simple<<<dim3(16, 64, 4), 64, 0, stream>>>(qkv, yb);
  cvt_bf16<<<dim3(512), 256, 0, stream>>>(w_proj, wpb, (long)1024 * 1024 / 8);
  // out = y @ w_proj^T  (f32 output)
  gemm_lds<true><<<dim3(1024), 256, 0, stream>>>(yb, wpb, out, 16384, 1024, 1024);
}

// Round 3
// 351.019 us; speedup vs baseline: 3.6195x; 1.3264x over previous
//
#include <hip/hip_runtime.h>
#include <math.h>

typedef __attribute__((ext_vector_type(8))) short short8;
typedef __attribute__((ext_vector_type(4))) short s16x4;
typedef __attribute__((ext_vector_type(4))) float floatx4;

__device__ __forceinline__ float bits2f(short u) {
  unsigned int x = ((unsigned int)(unsigned short)u) << 16;
  return __builtin_bit_cast(float, x);
}
__device__ __forceinline__ short f2bits(float f) {
  unsigned int x = __builtin_bit_cast(unsigned int, f);
  x += 0x7FFFu + ((x >> 16) & 1u);   // RNE
  return (short)(x >> 16);
}

__device__ __forceinline__ void gload_lds16(const short* g, short* l) {
  __builtin_amdgcn_global_load_lds((const __attribute__((address_space(1))) void*)g,
                                   (__attribute__((address_space(3))) void*)l, 16, 0, 0);
}

// ---------------------------------------------------------------------------
// f32 -> bf16 (RNE), 8 elems/thread, grid-stride. n8 = n_elems/8.
// ---------------------------------------------------------------------------
__global__ __launch_bounds__(256) void cvt_bf16(const float* __restrict__ in,
                                                short* __restrict__ out, long n8) {
  long i = (long)blockIdx.x * 256 + threadIdx.x;
  const long stride = (long)gridDim.x * 256;
  for (; i < n8; i += stride) {
    const floatx4* p = (const floatx4*)(in + i * 8);
    floatx4 v0 = p[0], v1 = p[1];
    short8 o;
#pragma unroll
    for (int e = 0; e < 4; e++) { o[e] = f2bits(v0[e]); o[e + 4] = f2bits(v1[e]); }
    *(short8*)(out + i * 8) = o;
  }
}

// ---------------------------------------------------------------------------
// rope table: tab[t][j] = {cos(t*inv_j), sin(t*inv_j)} interleaved f32,
// t in [0,64), j in [0,32).  2048 float2 entries = 16 KiB.
// ---------------------------------------------------------------------------
__global__ __launch_bounds__(256) void rope_table(float* __restrict__ tab) {
  int i = blockIdx.x * 256 + threadIdx.x;   // 0..2047
  if (i >= 64 * 32) return;
  int t = i >> 5, j = i & 31;
  float inv = exp2f(-(float)j * 0.41524101186092030f);  // 10000^(-j/32)
  float ang = (float)t * inv;
  tab[i * 2]     = cosf(ang);
  tab[i * 2 + 1] = sinf(ang);
}

// ---------------------------------------------------------------------------
// C[m][n] = sum_k A[m][k]*B[n][k], bf16 A/B (K-contiguous), fp32 acc.
// m97 structure: 128x128 block tile, BK=32, 4 waves (2x2), global_load_lds
// width-16 staging, ds_read_b128 fragments, 16 MFMA/K-step.
// Requires M%128==0, N%128==0, K%32==0, gridDim.x%8==0 (XCD swizzle).
// ---------------------------------------------------------------------------
template <bool COUT_F32>
__global__ __launch_bounds__(256) void gemm_lds(const short* __restrict__ A,
                                                const short* __restrict__ B,
                                                void* __restrict__ C,
                                                int M, int N, int K) {
  __shared__ __attribute__((aligned(16))) short sA[128 * 32];
  __shared__ __attribute__((aligned(16))) short sB[128 * 32];

  const int tid  = threadIdx.x;
  const int lane = tid & 63;
  const int wave = tid >> 6;
  const int frow = lane & 15;
  const int quad = lane >> 4;

  // bijective XCD-aware swizzle (gridDim.x % 8 == 0)
  const int nwg = gridDim.x;
  const int cpx = nwg >> 3;
  const int bid = blockIdx.x;
  const int swz = (bid & 7) * cpx + (bid >> 3);
  const int nbx = N >> 7;
  const int bx  = swz % nbx;
  const int by  = swz / nbx;

  const long m0 = (long)by * 128;
  const long n0 = (long)bx * 128;

  const int  c0    = tid;
  const long aoff  = (m0 + (c0 >> 2)) * (long)K + (c0 & 3) * 8;
  const long boff  = (n0 + (c0 >> 2)) * (long)K + (c0 & 3) * 8;
  const long rstep = 64L * K;

  floatx4 acc[4][4];
#pragma unroll
  for (int i = 0; i < 4; i++)
#pragma unroll
    for (int j = 0; j < 4; j++) acc[i][j] = (floatx4){0.f, 0.f, 0.f, 0.f};

  const int arow = (wave >> 1) * 64 + frow;
  const int brow = (wave &  1) * 64 + frow;

  for (int k0 = 0; k0 < K; k0 += 32) {
    __syncthreads();
    gload_lds16(A + aoff + k0,         sA + c0 * 8);
    gload_lds16(A + aoff + rstep + k0, sA + c0 * 8 + 2048);
    gload_lds16(B + boff + k0,         sB + c0 * 8);
    gload_lds16(B + boff + rstep + k0, sB + c0 * 8 + 2048);
    __syncthreads();

    short8 a[4], b[4];
#pragma unroll
    for (int i = 0; i < 4; i++) a[i] = *(const short8*)&sA[(arow + i * 16) * 32 + quad * 8];
#pragma unroll
    for (int i = 0; i < 4; i++) b[i] = *(const short8*)&sB[(brow + i * 16) * 32 + quad * 8];
#pragma unroll
    for (int mi = 0; mi < 4; mi++)
#pragma unroll
      for (int ni = 0; ni < 4; ni++)
        acc[mi][ni] = __builtin_amdgcn_mfma_f32_16x16x32_bf16(a[mi], b[ni], acc[mi][ni], 0, 0, 0);
  }

  const long mrow0 = m0 + (wave >> 1) * 64;
  const long ncol0 = n0 + (wave &  1) * 64;
#pragma unroll
  for (int mi = 0; mi < 4; mi++)
#pragma unroll
    for (int ni = 0; ni < 4; ni++) {
      long row0 = mrow0 + mi * 16 + quad * 4;
      long col  = ncol0 + ni * 16 + frow;
#pragma unroll
      for (int r = 0; r < 4; r++) {
        if constexpr (COUT_F32)
          ((float*)C)[(row0 + r) * (long)N + col] = acc[mi][ni][r];
        else
          ((short*)C)[(row0 + r) * (long)N + col] = f2bits(acc[mi][ni][r]);
      }
    }
}

// ---------------------------------------------------------------------------
// MFMA attention: 1 wave per (head, chunk, batch). Two 64x64x64 bt-GEMMs
// (S = Q.K^T, Y = P.V) on the matrix pipe; wave-parallel softmax via
// shfl_xor within 16-lane row groups. Rope applied in-register from table.
// Frag conventions identical to gemm_lds (verified): A/B row=lane&15,
// k-contig 8 at quad*8; C/D row=quad*4+r, col=lane&15.
// ---------------------------------------------------------------------------
__global__ __launch_bounds__(64, 1) void attn_mfma(const short* __restrict__ qkv,
                                                   short* __restrict__ y,
                                                   const float* __restrict__ cstab) {
  const int lane = threadIdx.x;
  const int frow = lane & 15;
  const int quad = lane >> 4;
  const int h = blockIdx.x, chunk = blockIdx.y, b = blockIdx.z;
  const long rowbase = (long)b * 4096 + (long)chunk * 64;

  __shared__ __attribute__((aligned(16))) short vt[64][68];  // V^T: vt[d][j]
  __shared__ __attribute__((aligned(16))) short ps[64][68];  // P / Y staging

  const short* qb = qkv + rowbase * 3072 + h * 64;

  // ---- Q,K fragments from global + in-register rope -> bf16 ----
  short8 qf[4][2], kf[4][2];
#pragma unroll
  for (int i = 0; i < 4; i++) {
    const short* rq = qb + (long)(16 * i + frow) * 3072 + quad * 8;
    qf[i][0] = *(const short8*)(rq);          // d = quad*8 + e
    qf[i][1] = *(const short8*)(rq + 32);     // d = 32 + quad*8 + e
    kf[i][0] = *(const short8*)(rq + 1024);
    kf[i][1] = *(const short8*)(rq + 1056);
    const floatx4* tp = (const floatx4*)(cstab + ((16 * i + frow) * 32 + quad * 8) * 2);
    floatx4 tv0 = tp[0], tv1 = tp[1], tv2 = tp[2], tv3 = tp[3];
#define CS_(k) ((k) < 4 ? tv0[(k) & 3] : (k) < 8 ? tv1[(k) & 3] : (k) < 12 ? tv2[(k) & 3] : tv3[(k) & 3])
#pragma unroll
    for (int e = 0; e < 8; e++) {
      float c = CS_(2 * e), s = CS_(2 * e + 1);
      float a0 = bits2f(qf[i][0][e]), a1 = bits2f(qf[i][1][e]);
      qf[i][0][e] = f2bits(a0 * c + a1 * s);
      qf[i][1][e] = f2bits(a1 * c - a0 * s);
      float b0 = bits2f(kf[i][0][e]), b1 = bits2f(kf[i][1][e]);
      kf[i][0][e] = f2bits(b0 * c + b1 * s);
      kf[i][1][e] = f2bits(b1 * c - b0 * s);
    }
#undef CS_
  }

  // ---- V -> LDS transposed (coalesced row loads, contiguous lane writes) ----
  const short* vb = qb + 2048 + (long)lane * 3072;
#pragma unroll
  for (int w = 0; w < 8; w++) {
    short8 v8 = *(const short8*)(vb + w * 8);
#pragma unroll
    for (int e = 0; e < 8; e++) vt[w * 8 + e][lane] = v8[e];
  }
  __syncthreads();

  // ---- S = Q.K^T (32 MFMAs) ----
  floatx4 sc[4][4];
#pragma unroll
  for (int mi = 0; mi < 4; mi++)
#pragma unroll
    for (int ni = 0; ni < 4; ni++) {
      sc[mi][ni] = (floatx4){0.f, 0.f, 0.f, 0.f};
      sc[mi][ni] = __builtin_amdgcn_mfma_f32_16x16x32_bf16(qf[mi][0], kf[ni][0], sc[mi][ni], 0, 0, 0);
      sc[mi][ni] = __builtin_amdgcn_mfma_f32_16x16x32_bf16(qf[mi][1], kf[ni][1], sc[mi][ni], 0, 0, 0);
    }

  // ---- softmax over rows (row = mi*16 + quad*4 + r; cols across ni, frow) ----
  float is_[4][4];
#pragma unroll
  for (int mi = 0; mi < 4; mi++)
#pragma unroll
    for (int r = 0; r < 4; r++) {
      float mx = fmaxf(fmaxf(sc[mi][0][r], sc[mi][1][r]), fmaxf(sc[mi][2][r], sc[mi][3][r]));
      mx = fmaxf(mx, __shfl_xor(mx, 1));
      mx = fmaxf(mx, __shfl_xor(mx, 2));
      mx = fmaxf(mx, __shfl_xor(mx, 4));
      mx = fmaxf(mx, __shfl_xor(mx, 8));
      float sm = 0.f;
#pragma unroll
      for (int ni = 0; ni < 4; ni++) {
        float e_ = __expf((sc[mi][ni][r] - mx) * 0.125f);   // scale 1/sqrt(64)
        sc[mi][ni][r] = e_;
        sm += e_;
      }
      sm += __shfl_xor(sm, 1);
      sm += __shfl_xor(sm, 2);
      sm += __shfl_xor(sm, 4);
      sm += __shfl_xor(sm, 8);
      is_[mi][r] = 1.0f / sm;
    }

  // ---- P -> LDS bf16 ----
#pragma unroll
  for (int mi = 0; mi < 4; mi++)
#pragma unroll
    for (int ni = 0; ni < 4; ni++)
#pragma unroll
      for (int r = 0; r < 4; r++)
        ps[mi * 16 + quad * 4 + r][ni * 16 + frow] = f2bits(sc[mi][ni][r] * is_[mi][r]);
  __syncthreads();

  // ---- P, V^T fragments ----
  short8 pf[4][2], vf[4][2];
#pragma unroll
  for (int i = 0; i < 4; i++)
#pragma unroll
    for (int ks = 0; ks < 2; ks++) {
      const short* pp = &ps[frow + 16 * i][quad * 8 + 32 * ks];
      s16x4 p0 = *(const s16x4*)pp, p1 = *(const s16x4*)(pp + 4);
      const short* vp = &vt[frow + 16 * i][quad * 8 + 32 * ks];
      s16x4 v0 = *(const s16x4*)vp, v1 = *(const s16x4*)(vp + 4);
#pragma unroll
      for (int e = 0; e < 4; e++) {
        pf[i][ks][e] = p0[e]; pf[i][ks][e + 4] = p1[e];
        vf[i][ks][e] = v0[e]; vf[i][ks][e + 4] = v1[e];
      }
    }

  // ---- Y = P.V (32 MFMAs) ----
  floatx4 oc[4][4];
#pragma unroll
  for (int mi = 0; mi < 4; mi++)
#pragma unroll
    for (int ni = 0; ni < 4; ni++) {
      oc[mi][ni] = (floatx4){0.f, 0.f, 0.f, 0.f};
      oc[mi][ni] = __builtin_amdgcn_mfma_f32_16x16x32_bf16(pf[mi][0], vf[ni][0], oc[mi][ni], 0, 0, 0);
      oc[mi][ni] = __builtin_amdgcn_mfma_f32_16x16x32_bf16(pf[mi][1], vf[ni][1], oc[mi][ni], 0, 0, 0);
    }

  // ---- Y -> LDS -> coalesced global store ----
  __syncthreads();
#pragma unroll
  for (int mi = 0; mi < 4; mi++)
#pragma unroll
    for (int ni = 0; ni < 4; ni++)
#pragma unroll
      for (int r = 0; r < 4; r++)
        ps[mi * 16 + quad * 4 + r][ni * 16 + frow] = f2bits(oc[mi][ni][r]);
  __syncthreads();

  short* dst = y + (rowbase + lane) * 1024 + h * 64;
#pragma unroll
  for (int w = 0; w < 8; w++) {
    const short* rp = &ps[lane][w * 8];
    s16x4 o0 = *(const s16x4*)rp, o1 = *(const s16x4*)(rp + 4);
    short8 o8;
#pragma unroll
    for (int e = 0; e < 4; e++) { o8[e] = o0[e]; o8[e + 4] = o1[e]; }
    *(short8*)(dst + w * 8) = o8;
  }
}

// ---------------------------------------------------------------------------
extern "C" void kernel_launch(void* const* d_in, const int* in_sizes, int n_in,
                              void* d_out, int out_size, void* d_ws, size_t ws_size,
                              hipStream_t stream) {
  (void)in_sizes; (void)n_in; (void)out_size; (void)ws_size;
  const float* x      = (const float*)d_in[0];  // f32 (4,4096,1024)
  const float* w_attn = (const float*)d_in[1];  // f32 (3072,1024)
  const float* w_proj = (const float*)d_in[2];  // f32 (1024,1024)
  float* out = (float*)d_out;                   // f32 (4,4096,1024)

  // ws: qkv 96 MiB | yb 32 MiB.  wab overlaps yb (dead before attn writes yb);
  // wpb overlaps qkv (written after attn reads qkv).
  // d_out scratch: xb (bf16 x, first 32 MiB) + rope table (16 KiB at +32 MiB);
  // both dead before gemm2 overwrites all of out.
  short* qkv = (short*)d_ws;
  short* yb  = qkv + (size_t)16384 * 3072;
  short* wab = yb;
  short* wpb = qkv;
  short* xb  = (short*)d_out;
  float* tab = (float*)((char*)d_out + (size_t)32 * 1024 * 1024);

  cvt_bf16<<<dim3(2048), 256, 0, stream>>>(x,      xb,  (long)16384 * 1024 / 8);
  cvt_bf16<<<dim3(1024), 256, 0, stream>>>(w_attn, wab, (long)3072 * 1024 / 8);
  rope_table<<<dim3(8), 256, 0, stream>>>(tab);
  // qkv = x @ w_attn^T
  gemm_lds<false><<<dim3(3072), 256, 0, stream>>>(xb, wab, qkv, 16384, 3072, 1024);
  // chunked MFMA attention -> y (bf16)
  attn_mfma<<<dim3(16, 64, 4), 64, 0, stream>>>(qkv, yb, tab);
  cvt_bf16<<<dim3(512), 256, 0, stream>>>(w_proj, wpb, (long)1024 * 1024 / 8);
  // out = y @ w_proj^T  (f32 output)
  gemm_lds<true><<<dim3(1024), 256, 0, stream>>>(yb, wpb, out, 16384, 1024, 1024);
}

// Round 4
// 319.287 us; speedup vs baseline: 3.9792x; 1.0994x over previous
//
#include <hip/hip_runtime.h>
#include <math.h>

typedef __attribute__((ext_vector_type(8))) short short8;
typedef __attribute__((ext_vector_type(4))) short s16x4;
typedef __attribute__((ext_vector_type(4))) float floatx4;

__device__ __forceinline__ float bits2f(short u) {
  unsigned int x = ((unsigned int)(unsigned short)u) << 16;
  return __builtin_bit_cast(float, x);
}
__device__ __forceinline__ short f2bits(float f) {
  unsigned int x = __builtin_bit_cast(unsigned int, f);
  x += 0x7FFFu + ((x >> 16) & 1u);   // RNE
  return (short)(x >> 16);
}

__device__ __forceinline__ void gload_lds16(const short* g, short* l) {
  __builtin_amdgcn_global_load_lds((const __attribute__((address_space(1))) void*)g,
                                   (__attribute__((address_space(3))) void*)l, 16, 0, 0);
}

// ---------------------------------------------------------------------------
// f32 -> bf16 (RNE), 8 elems/thread, grid-stride. n8 = n_elems/8.
// ---------------------------------------------------------------------------
__global__ __launch_bounds__(256) void cvt_bf16(const float* __restrict__ in,
                                                short* __restrict__ out, long n8) {
  long i = (long)blockIdx.x * 256 + threadIdx.x;
  const long stride = (long)gridDim.x * 256;
  for (; i < n8; i += stride) {
    const floatx4* p = (const floatx4*)(in + i * 8);
    floatx4 v0 = p[0], v1 = p[1];
    short8 o;
#pragma unroll
    for (int e = 0; e < 4; e++) { o[e] = f2bits(v0[e]); o[e + 4] = f2bits(v1[e]); }
    *(short8*)(out + i * 8) = o;
  }
}

// ---------------------------------------------------------------------------
// rope table: tab[t][j] = {cos(t*inv_j), sin(t*inv_j)} interleaved f32.
// ---------------------------------------------------------------------------
__global__ __launch_bounds__(256) void rope_table(float* __restrict__ tab) {
  int i = blockIdx.x * 256 + threadIdx.x;   // 0..2047
  if (i >= 64 * 32) return;
  int t = i >> 5, j = i & 31;
  float inv = exp2f(-(float)j * 0.41524101186092030f);  // 10000^(-j/32)
  float ang = (float)t * inv;
  tab[i * 2]     = cosf(ang);
  tab[i * 2 + 1] = sinf(ang);
}

// ---------------------------------------------------------------------------
// C[m][n] = sum_k A[m][k]*B[n][k], bf16 in, fp32 acc. 256x256 tile, BK=32,
// 8 waves (2M x 4N, wave tile 128x64), ring-4 LDS pipeline (4 x 32KB slots),
// counted vmcnt (never 0 in main loop), raw s_barrier, setprio on MFMA.
// Requires M%256==0, N%256==0, K%32==0, K>=128, gridDim.x%8==0.
// ---------------------------------------------------------------------------
template <bool COUT_F32>
__global__ __launch_bounds__(512, 2) void gemm256(const short* __restrict__ A,
                                                  const short* __restrict__ B,
                                                  void* __restrict__ C,
                                                  int M, int N, int K) {
  (void)M;
  __shared__ __attribute__((aligned(16))) short lds[65536];  // 4 slots x (A 16KB | B 16KB)

  const int t    = threadIdx.x;          // 0..511
  const int lane = t & 63;
  const int wave = t >> 6;               // 0..7
  const int wm   = wave >> 2;            // 0..1
  const int wn   = wave & 3;             // 0..3
  const int frow = lane & 15;
  const int quad = lane >> 4;

  // bijective XCD-aware swizzle (gridDim.x % 8 == 0)
  const int nwg = gridDim.x;
  const int cpx = nwg >> 3;
  const int bid = blockIdx.x;
  const int swz = (bid & 7) * cpx + (bid >> 3);
  const int nbx = N >> 8;
  const int bx  = swz % nbx;
  const int by  = swz / nbx;
  const long m0 = (long)by * 256;
  const long n0 = (long)bx * 256;

  const int NT = K >> 5;                 // K-tiles of 32

  // staging: per matrix 16KB/tile = 512thr x 16B x 2 issues (rows 0-127, 128-255)
  const int  srow  = t >> 2;             // 0..127
  const int  scol  = (t & 3) * 8;
  const long aoff0 = (m0 + srow) * (long)K + scol;
  const long aoff1 = aoff0 + 128L * K;
  const long boff0 = (n0 + srow) * (long)K + scol;
  const long boff1 = boff0 + 128L * K;
  const int  t8    = t * 8;              // linear LDS dest (shorts)

  floatx4 acc[8][4];
#pragma unroll
  for (int i = 0; i < 8; i++)
#pragma unroll
    for (int j = 0; j < 4; j++) acc[i][j] = (floatx4){0.f, 0.f, 0.f, 0.f};

  // prologue: stage tiles 0,1,2 into slots 0,1,2 (12 issues/thread)
  for (int p = 0; p < 3; ++p) {
    short* la = lds + p * 16384;
    const long kk = (long)p * 32;
    gload_lds16(A + aoff0 + kk, la + t8);
    gload_lds16(A + aoff1 + kk, la + t8 + 4096);
    gload_lds16(B + boff0 + kk, la + 8192 + t8);
    gload_lds16(B + boff1 + kk, la + 8192 + t8 + 4096);
  }

#define GSTEP(KT, VMSTR, DO_STAGE)                                                     \
  {                                                                                    \
    const int kt_ = (KT);                                                              \
    asm volatile("s_barrier" ::: "memory");  /* all waves done reading slot kt_-1 */   \
    if (DO_STAGE) {                                                                    \
      short* sa = lds + ((kt_ + 3) & 3) * 16384;                                       \
      const long kk = (long)(kt_ + 3) * 32;                                            \
      gload_lds16(A + aoff0 + kk, sa + t8);                                            \
      gload_lds16(A + aoff1 + kk, sa + t8 + 4096);                                     \
    }                                                                                  \
    asm volatile("s_waitcnt " VMSTR ::: "memory");  /* own share of tile kt_ landed */ \
    asm volatile("s_barrier" ::: "memory");         /* everyone's share landed */      \
    {                                                                                  \
      const short* la = lds + (kt_ & 3) * 16384;                                       \
      const short* lb = la + 8192;                                                     \
      short8 af[8], bf[4];                                                             \
      _Pragma("unroll")                                                                \
      for (int ni = 0; ni < 4; ni++)                                                   \
        bf[ni] = *(const short8*)&lb[(wn * 64 + ni * 16 + frow) * 32 + quad * 8];      \
      _Pragma("unroll")                                                                \
      for (int mi = 0; mi < 8; mi++)                                                   \
        af[mi] = *(const short8*)&la[(wm * 128 + mi * 16 + frow) * 32 + quad * 8];     \
      __builtin_amdgcn_s_setprio(1);                                                   \
      _Pragma("unroll")                                                                \
      for (int mi = 0; mi < 4; mi++)                                                   \
        _Pragma("unroll")                                                              \
        for (int ni = 0; ni < 4; ni++)                                                 \
          acc[mi][ni] =                                                                \
              __builtin_amdgcn_mfma_f32_16x16x32_bf16(af[mi], bf[ni], acc[mi][ni], 0, 0, 0); \
      __builtin_amdgcn_s_setprio(0);                                                   \
      if (DO_STAGE) {                                                                  \
        short* sb = lds + ((kt_ + 3) & 3) * 16384;                                     \
        const long kk = (long)(kt_ + 3) * 32;                                          \
        gload_lds16(B + boff0 + kk, sb + 8192 + t8);                                   \
        gload_lds16(B + boff1 + kk, sb + 8192 + t8 + 4096);                            \
      }                                                                                \
      __builtin_amdgcn_s_setprio(1);                                                   \
      _Pragma("unroll")                                                                \
      for (int mi = 4; mi < 8; mi++)                                                   \
        _Pragma("unroll")                                                              \
        for (int ni = 0; ni < 4; ni++)                                                 \
          acc[mi][ni] =                                                                \
              __builtin_amdgcn_mfma_f32_16x16x32_bf16(af[mi], bf[ni], acc[mi][ni], 0, 0, 0); \
      __builtin_amdgcn_s_setprio(0);                                                   \
    }                                                                                  \
  }

  // main loop: tiles kt+1,kt+2 fully in flight + stageA(kt+3) = 10 outstanding
  for (int kt = 0; kt <= NT - 4; ++kt) GSTEP(kt, "vmcnt(10)", true);
  GSTEP(NT - 3, "vmcnt(8)", false);
  GSTEP(NT - 2, "vmcnt(4)", false);
  GSTEP(NT - 1, "vmcnt(0)", false);
#undef GSTEP

  // epilogue: C/D layout col=lane&15, row=quad*4+r (verified convention)
  const long mrow0 = m0 + wm * 128;
  const long ncol0 = n0 + wn * 64;
#pragma unroll
  for (int mi = 0; mi < 8; mi++)
#pragma unroll
    for (int ni = 0; ni < 4; ni++) {
      long row0 = mrow0 + mi * 16 + quad * 4;
      long col  = ncol0 + ni * 16 + frow;
#pragma unroll
      for (int r = 0; r < 4; r++) {
        if constexpr (COUT_F32)
          ((float*)C)[(row0 + r) * (long)N + col] = acc[mi][ni][r];
        else
          ((short*)C)[(row0 + r) * (long)N + col] = f2bits(acc[mi][ni][r]);
      }
    }
}

// ---------------------------------------------------------------------------
// MFMA attention: 1 wave per (head, chunk, batch). Two 64x64x64 bt-GEMMs
// (S = Q.K^T, Y = P.V); wave-parallel softmax via shfl_xor in 16-lane groups.
// ---------------------------------------------------------------------------
__global__ __launch_bounds__(64, 1) void attn_mfma(const short* __restrict__ qkv,
                                                   short* __restrict__ y,
                                                   const float* __restrict__ cstab) {
  const int lane = threadIdx.x;
  const int frow = lane & 15;
  const int quad = lane >> 4;
  const int h = blockIdx.x, chunk = blockIdx.y, b = blockIdx.z;
  const long rowbase = (long)b * 4096 + (long)chunk * 64;

  __shared__ __attribute__((aligned(16))) short vt[64][68];  // V^T: vt[d][j]
  __shared__ __attribute__((aligned(16))) short ps[64][68];  // P / Y staging

  const short* qb = qkv + rowbase * 3072 + h * 64;

  // ---- Q,K fragments from global + in-register rope -> bf16 ----
  short8 qf[4][2], kf[4][2];
#pragma unroll
  for (int i = 0; i < 4; i++) {
    const short* rq = qb + (long)(16 * i + frow) * 3072 + quad * 8;
    qf[i][0] = *(const short8*)(rq);
    qf[i][1] = *(const short8*)(rq + 32);
    kf[i][0] = *(const short8*)(rq + 1024);
    kf[i][1] = *(const short8*)(rq + 1056);
    const floatx4* tp = (const floatx4*)(cstab + ((16 * i + frow) * 32 + quad * 8) * 2);
    floatx4 tv0 = tp[0], tv1 = tp[1], tv2 = tp[2], tv3 = tp[3];
#define CS_(k) ((k) < 4 ? tv0[(k) & 3] : (k) < 8 ? tv1[(k) & 3] : (k) < 12 ? tv2[(k) & 3] : tv3[(k) & 3])
#pragma unroll
    for (int e = 0; e < 8; e++) {
      float c = CS_(2 * e), s = CS_(2 * e + 1);
      float a0 = bits2f(qf[i][0][e]), a1 = bits2f(qf[i][1][e]);
      qf[i][0][e] = f2bits(a0 * c + a1 * s);
      qf[i][1][e] = f2bits(a1 * c - a0 * s);
      float b0 = bits2f(kf[i][0][e]), b1 = bits2f(kf[i][1][e]);
      kf[i][0][e] = f2bits(b0 * c + b1 * s);
      kf[i][1][e] = f2bits(b1 * c - b0 * s);
    }
#undef CS_
  }

  // ---- V -> LDS transposed ----
  const short* vb = qb + 2048 + (long)lane * 3072;
#pragma unroll
  for (int w = 0; w < 8; w++) {
    short8 v8 = *(const short8*)(vb + w * 8);
#pragma unroll
    for (int e = 0; e < 8; e++) vt[w * 8 + e][lane] = v8[e];
  }
  __syncthreads();

  // ---- S = Q.K^T ----
  floatx4 sc[4][4];
#pragma unroll
  for (int mi = 0; mi < 4; mi++)
#pragma unroll
    for (int ni = 0; ni < 4; ni++) {
      sc[mi][ni] = (floatx4){0.f, 0.f, 0.f, 0.f};
      sc[mi][ni] = __builtin_amdgcn_mfma_f32_16x16x32_bf16(qf[mi][0], kf[ni][0], sc[mi][ni], 0, 0, 0);
      sc[mi][ni] = __builtin_amdgcn_mfma_f32_16x16x32_bf16(qf[mi][1], kf[ni][1], sc[mi][ni], 0, 0, 0);
    }

  // ---- softmax ----
  float is_[4][4];
#pragma unroll
  for (int mi = 0; mi < 4; mi++)
#pragma unroll
    for (int r = 0; r < 4; r++) {
      float mx = fmaxf(fmaxf(sc[mi][0][r], sc[mi][1][r]), fmaxf(sc[mi][2][r], sc[mi][3][r]));
      mx = fmaxf(mx, __shfl_xor(mx, 1));
      mx = fmaxf(mx, __shfl_xor(mx, 2));
      mx = fmaxf(mx, __shfl_xor(mx, 4));
      mx = fmaxf(mx, __shfl_xor(mx, 8));
      float sm = 0.f;
#pragma unroll
      for (int ni = 0; ni < 4; ni++) {
        float e_ = __expf((sc[mi][ni][r] - mx) * 0.125f);
        sc[mi][ni][r] = e_;
        sm += e_;
      }
      sm += __shfl_xor(sm, 1);
      sm += __shfl_xor(sm, 2);
      sm += __shfl_xor(sm, 4);
      sm += __shfl_xor(sm, 8);
      is_[mi][r] = 1.0f / sm;
    }

  // ---- P -> LDS bf16 ----
#pragma unroll
  for (int mi = 0; mi < 4; mi++)
#pragma unroll
    for (int ni = 0; ni < 4; ni++)
#pragma unroll
      for (int r = 0; r < 4; r++)
        ps[mi * 16 + quad * 4 + r][ni * 16 + frow] = f2bits(sc[mi][ni][r] * is_[mi][r]);
  __syncthreads();

  // ---- P, V^T fragments ----
  short8 pf[4][2], vf[4][2];
#pragma unroll
  for (int i = 0; i < 4; i++)
#pragma unroll
    for (int ks = 0; ks < 2; ks++) {
      const short* pp = &ps[frow + 16 * i][quad * 8 + 32 * ks];
      s16x4 p0 = *(const s16x4*)pp, p1 = *(const s16x4*)(pp + 4);
      const short* vp = &vt[frow + 16 * i][quad * 8 + 32 * ks];
      s16x4 v0 = *(const s16x4*)vp, v1 = *(const s16x4*)(vp + 4);
#pragma unroll
      for (int e = 0; e < 4; e++) {
        pf[i][ks][e] = p0[e]; pf[i][ks][e + 4] = p1[e];
        vf[i][ks][e] = v0[e]; vf[i][ks][e + 4] = v1[e];
      }
    }

  // ---- Y = P.V ----
  floatx4 oc[4][4];
#pragma unroll
  for (int mi = 0; mi < 4; mi++)
#pragma unroll
    for (int ni = 0; ni < 4; ni++) {
      oc[mi][ni] = (floatx4){0.f, 0.f, 0.f, 0.f};
      oc[mi][ni] = __builtin_amdgcn_mfma_f32_16x16x32_bf16(pf[mi][0], vf[ni][0], oc[mi][ni], 0, 0, 0);
      oc[mi][ni] = __builtin_amdgcn_mfma_f32_16x16x32_bf16(pf[mi][1], vf[ni][1], oc[mi][ni], 0, 0, 0);
    }

  // ---- Y -> LDS -> coalesced global store ----
  __syncthreads();
#pragma unroll
  for (int mi = 0; mi < 4; mi++)
#pragma unroll
    for (int ni = 0; ni < 4; ni++)
#pragma unroll
      for (int r = 0; r < 4; r++)
        ps[mi * 16 + quad * 4 + r][ni * 16 + frow] = f2bits(oc[mi][ni][r]);
  __syncthreads();

  short* dst = y + (rowbase + lane) * 1024 + h * 64;
#pragma unroll
  for (int w = 0; w < 8; w++) {
    const short* rp = &ps[lane][w * 8];
    s16x4 o0 = *(const s16x4*)rp, o1 = *(const s16x4*)(rp + 4);
    short8 o8;
#pragma unroll
    for (int e = 0; e < 4; e++) { o8[e] = o0[e]; o8[e + 4] = o1[e]; }
    *(short8*)(dst + w * 8) = o8;
  }
}

// ---------------------------------------------------------------------------
extern "C" void kernel_launch(void* const* d_in, const int* in_sizes, int n_in,
                              void* d_out, int out_size, void* d_ws, size_t ws_size,
                              hipStream_t stream) {
  (void)in_sizes; (void)n_in; (void)out_size; (void)ws_size;
  const float* x      = (const float*)d_in[0];  // f32 (4,4096,1024)
  const float* w_attn = (const float*)d_in[1];  // f32 (3072,1024)
  const float* w_proj = (const float*)d_in[2];  // f32 (1024,1024)
  float* out = (float*)d_out;                   // f32 (4,4096,1024)

  // ws: qkv 96 MiB | yb 32 MiB.  wab overlaps yb (dead before attn writes yb);
  // wpb overlaps qkv (written after attn reads qkv).
  // d_out scratch: xb (bf16 x, 32 MiB) + rope table (16 KiB at +32 MiB);
  // both dead before gemm2 overwrites all of out.
  short* qkv = (short*)d_ws;
  short* yb  = qkv + (size_t)16384 * 3072;
  short* wab = yb;
  short* wpb = qkv;
  short* xb  = (short*)d_out;
  float* tab = (float*)((char*)d_out + (size_t)32 * 1024 * 1024);

  cvt_bf16<<<dim3(2048), 256, 0, stream>>>(x,      xb,  (long)16384 * 1024 / 8);
  cvt_bf16<<<dim3(1024), 256, 0, stream>>>(w_attn, wab, (long)3072 * 1024 / 8);
  rope_table<<<dim3(8), 256, 0, stream>>>(tab);
  // qkv = x @ w_attn^T   (16384x3072x1024): grid 64x12 = 768 blocks
  gemm256<false><<<dim3(768), 512, 0, stream>>>(xb, wab, qkv, 16384, 3072, 1024);
  // chunked MFMA attention -> y (bf16)
  attn_mfma<<<dim3(16, 64, 4), 64, 0, stream>>>(qkv, yb, tab);
  cvt_bf16<<<dim3(512), 256, 0, stream>>>(w_proj, wpb, (long)1024 * 1024 / 8);
  // out = y @ w_proj^T   (16384x1024x1024): grid 64x4 = 256 blocks, f32 out
  gemm256<true><<<dim3(256), 512, 0, stream>>>(yb, wpb, out, 16384, 1024, 1024);
}

// Round 7
// 311.361 us; speedup vs baseline: 4.0805x; 1.0255x over previous
//
#include <hip/hip_runtime.h>
#include <math.h>

typedef __attribute__((ext_vector_type(8))) short short8;
typedef __attribute__((ext_vector_type(4))) short s16x4;
typedef __attribute__((ext_vector_type(4))) float floatx4;

__device__ __forceinline__ float bits2f(short u) {
  unsigned int x = ((unsigned int)(unsigned short)u) << 16;
  return __builtin_bit_cast(float, x);
}
__device__ __forceinline__ short f2bits(float f) {
  unsigned int x = __builtin_bit_cast(unsigned int, f);
  x += 0x7FFFu + ((x >> 16) & 1u);   // RNE
  return (short)(x >> 16);
}

__device__ __forceinline__ void gload_lds16(const short* g, short* l) {
  __builtin_amdgcn_global_load_lds((const __attribute__((address_space(1))) void*)g,
                                   (__attribute__((address_space(3))) void*)l, 16, 0, 0);
}

// ---------------------------------------------------------------------------
// f32 -> bf16 (RNE), 8 elems/thread, grid-stride. n8 = n_elems/8.
// ---------------------------------------------------------------------------
__global__ __launch_bounds__(256) void cvt_bf16(const float* __restrict__ in,
                                                short* __restrict__ out, long n8) {
  long i = (long)blockIdx.x * 256 + threadIdx.x;
  const long stride = (long)gridDim.x * 256;
  for (; i < n8; i += stride) {
    const floatx4* p = (const floatx4*)(in + i * 8);
    floatx4 v0 = p[0], v1 = p[1];
    short8 o;
#pragma unroll
    for (int e = 0; e < 4; e++) { o[e] = f2bits(v0[e]); o[e + 4] = f2bits(v1[e]); }
    *(short8*)(out + i * 8) = o;
  }
}

// ---------------------------------------------------------------------------
// rope table: tab[t][j] = {cos(t*inv_j), sin(t*inv_j)} interleaved f32.
// ---------------------------------------------------------------------------
__global__ __launch_bounds__(256) void rope_table(float* __restrict__ tab) {
  int i = blockIdx.x * 256 + threadIdx.x;   // 0..2047
  if (i >= 64 * 32) return;
  int t = i >> 5, j = i & 31;
  float inv = exp2f(-(float)j * 0.41524101186092030f);  // 10000^(-j/32)
  float ang = (float)t * inv;
  tab[i * 2]     = cosf(ang);
  tab[i * 2 + 1] = sinf(ang);
}

// ---------------------------------------------------------------------------
// C[m][n] = sum_k A[m][k]*B[n][k], bf16 in, fp32 acc. 256x256 tile, BK=32,
// 8 waves (2M x 4N, wave tile 128x64), ring-4 LDS pipeline (4 x 32KB slots),
// counted vmcnt (never 0 in main loop), raw s_barrier, setprio on MFMA.
// Bank swizzle (rule 21 both-sides): LDS dest stays linear for
// global_load_lds; the global SOURCE k-chunk is permuted slot^((row>>1)&3)
// and the ds_read applies the same involution -> each 8-lane phase of a
// ds_read_b128 hits 8 distinct 16B bank-quartets (conflict-free).
// Requires M%256==0, N%256==0, K%32==0, K>=128, gridDim.x%8==0.
// ---------------------------------------------------------------------------
template <bool COUT_F32>
__global__ __launch_bounds__(512, 2) void gemm256(const short* __restrict__ A,
                                                  const short* __restrict__ B,
                                                  void* __restrict__ C,
                                                  int M, int N, int K) {
  (void)M;
  __shared__ __attribute__((aligned(16))) short lds[65536];  // 4 slots x (A 16KB | B 16KB)

  const int t    = threadIdx.x;          // 0..511
  const int lane = t & 63;
  const int wave = t >> 6;               // 0..7
  const int wm   = wave >> 2;            // 0..1
  const int wn   = wave & 3;             // 0..3
  const int frow = lane & 15;
  const int quad = lane >> 4;

  // bijective XCD-aware swizzle (gridDim.x % 8 == 0)
  const int nwg = gridDim.x;
  const int cpx = nwg >> 3;
  const int bid = blockIdx.x;
  const int swz = (bid & 7) * cpx + (bid >> 3);
  const int nbx = N >> 8;
  const int bx  = swz % nbx;
  const int by  = swz / nbx;
  const long m0 = (long)by * 256;
  const long n0 = (long)bx * 256;

  const int NT = K >> 5;                 // K-tiles of 32

  // staging: per matrix 16KB/tile = 512thr x 16B x 2 issues (rows 0-127, 128-255)
  // thread t -> LDS (row=t>>2, slot=t&3) linear; global k-chunk = slot^((row>>1)&3)
  const int  srow  = t >> 2;             // 0..127
  const int  scol  = ((t & 3) ^ ((srow >> 1) & 3)) * 8;   // pre-permuted source col
  const long aoff0 = (m0 + srow) * (long)K + scol;
  const long aoff1 = aoff0 + 128L * K;   // rows 128..255: (row>>1)&3 unchanged
  const long boff0 = (n0 + srow) * (long)K + scol;
  const long boff1 = boff0 + 128L * K;
  const int  t8    = t * 8;              // linear LDS dest (shorts)

  // fragment read: logical k-chunk quad lives at LDS slot quad^((frow>>1)&3)
  const int sw8 = (quad ^ ((frow >> 1) & 3)) * 8;

  floatx4 acc[8][4];
#pragma unroll
  for (int i = 0; i < 8; i++)
#pragma unroll
    for (int j = 0; j < 4; j++) acc[i][j] = (floatx4){0.f, 0.f, 0.f, 0.f};

  // prologue: stage tiles 0,1,2 into slots 0,1,2 (12 issues/thread)
  for (int p = 0; p < 3; ++p) {
    short* la = lds + p * 16384;
    const long kk = (long)p * 32;
    gload_lds16(A + aoff0 + kk, la + t8);
    gload_lds16(A + aoff1 + kk, la + t8 + 4096);
    gload_lds16(B + boff0 + kk, la + 8192 + t8);
    gload_lds16(B + boff1 + kk, la + 8192 + t8 + 4096);
  }

#define GSTEP(KT, VMSTR, DO_STAGE)                                                     \
  {                                                                                    \
    const int kt_ = (KT);                                                              \
    asm volatile("s_barrier" ::: "memory");  /* all waves done reading slot kt_-1 */   \
    if (DO_STAGE) {                                                                    \
      short* sa = lds + ((kt_ + 3) & 3) * 16384;                                       \
      const long kk = (long)(kt_ + 3) * 32;                                            \
      gload_lds16(A + aoff0 + kk, sa + t8);                                            \
      gload_lds16(A + aoff1 + kk, sa + t8 + 4096);                                     \
    }                                                                                  \
    asm volatile("s_waitcnt " VMSTR ::: "memory");  /* own share of tile kt_ landed */ \
    asm volatile("s_barrier" ::: "memory");         /* everyone's share landed */      \
    {                                                                                  \
      const short* la = lds + (kt_ & 3) * 16384;                                       \
      const short* lb = la + 8192;                                                     \
      short8 af[8], bf[4];                                                             \
      _Pragma("unroll")                                                                \
      for (int ni = 0; ni < 4; ni++)                                                   \
        bf[ni] = *(const short8*)&lb[(wn * 64 + ni * 16 + frow) * 32 + sw8];           \
      _Pragma("unroll")                                                                \
      for (int mi = 0; mi < 8; mi++)                                                   \
        af[mi] = *(const short8*)&la[(wm * 128 + mi * 16 + frow) * 32 + sw8];          \
      __builtin_amdgcn_s_setprio(1);                                                   \
      _Pragma("unroll")                                                                \
      for (int mi = 0; mi < 4; mi++)                                                   \
        _Pragma("unroll")                                                              \
        for (int ni = 0; ni < 4; ni++)                                                 \
          acc[mi][ni] =                                                                \
              __builtin_amdgcn_mfma_f32_16x16x32_bf16(af[mi], bf[ni], acc[mi][ni], 0, 0, 0); \
      __builtin_amdgcn_s_setprio(0);                                                   \
      if (DO_STAGE) {                                                                  \
        short* sb = lds + ((kt_ + 3) & 3) * 16384;                                     \
        const long kk = (long)(kt_ + 3) * 32;                                          \
        gload_lds16(B + boff0 + kk, sb + 8192 + t8);                                   \
        gload_lds16(B + boff1 + kk, sb + 8192 + t8 + 4096);                            \
      }                                                                                \
      __builtin_amdgcn_s_setprio(1);                                                   \
      _Pragma("unroll")                                                                \
      for (int mi = 4; mi < 8; mi++)                                                   \
        _Pragma("unroll")                                                              \
        for (int ni = 0; ni < 4; ni++)                                                 \
          acc[mi][ni] =                                                                \
              __builtin_amdgcn_mfma_f32_16x16x32_bf16(af[mi], bf[ni], acc[mi][ni], 0, 0, 0); \
      __builtin_amdgcn_s_setprio(0);                                                   \
    }                                                                                  \
  }

  // main loop: tiles kt+1,kt+2 fully in flight + stageA(kt+3) = 10 outstanding
  for (int kt = 0; kt <= NT - 4; ++kt) GSTEP(kt, "vmcnt(10)", true);
  GSTEP(NT - 3, "vmcnt(8)", false);
  GSTEP(NT - 2, "vmcnt(4)", false);
  GSTEP(NT - 1, "vmcnt(0)", false);
#undef GSTEP

  // epilogue: C/D layout col=lane&15, row=quad*4+r (verified convention)
  const long mrow0 = m0 + wm * 128;
  const long ncol0 = n0 + wn * 64;
#pragma unroll
  for (int mi = 0; mi < 8; mi++)
#pragma unroll
    for (int ni = 0; ni < 4; ni++) {
      long row0 = mrow0 + mi * 16 + quad * 4;
      long col  = ncol0 + ni * 16 + frow;
#pragma unroll
      for (int r = 0; r < 4; r++) {
        if constexpr (COUT_F32)
          ((float*)C)[(row0 + r) * (long)N + col] = acc[mi][ni][r];
        else
          ((short*)C)[(row0 + r) * (long)N + col] = f2bits(acc[mi][ni][r]);
      }
    }
}

// ---------------------------------------------------------------------------
// MFMA attention: 1 wave per (head, chunk, batch). Two 64x64x64 bt-GEMMs
// (S = Q.K^T, Y = P.V); wave-parallel softmax via shfl_xor in 16-lane groups.
// ---------------------------------------------------------------------------
__global__ __launch_bounds__(64, 1) void attn_mfma(const short* __restrict__ qkv,
                                                   short* __restrict__ y,
                                                   const float* __restrict__ cstab) {
  const int lane = threadIdx.x;
  const int frow = lane & 15;
  const int quad = lane >> 4;
  const int h = blockIdx.x, chunk = blockIdx.y, b = blockIdx.z;
  const long rowbase = (long)b * 4096 + (long)chunk * 64;

  __shared__ __attribute__((aligned(16))) short vt[64][68];  // V^T: vt[d][j]
  __shared__ __attribute__((aligned(16))) short ps[64][68];  // P / Y staging

  const short* qb = qkv + rowbase * 3072 + h * 64;

  // ---- Q,K fragments from global + in-register rope -> bf16 ----
  short8 qf[4][2], kf[4][2];
#pragma unroll
  for (int i = 0; i < 4; i++) {
    const short* rq = qb + (long)(16 * i + frow) * 3072 + quad * 8;
    qf[i][0] = *(const short8*)(rq);
    qf[i][1] = *(const short8*)(rq + 32);
    kf[i][0] = *(const short8*)(rq + 1024);
    kf[i][1] = *(const short8*)(rq + 1056);
    const floatx4* tp = (const floatx4*)(cstab + ((16 * i + frow) * 32 + quad * 8) * 2);
    floatx4 tv0 = tp[0], tv1 = tp[1], tv2 = tp[2], tv3 = tp[3];
#define CS_(k) ((k) < 4 ? tv0[(k) & 3] : (k) < 8 ? tv1[(k) & 3] : (k) < 12 ? tv2[(k) & 3] : tv3[(k) & 3])
#pragma unroll
    for (int e = 0; e < 8; e++) {
      float c = CS_(2 * e), s = CS_(2 * e + 1);
      float a0 = bits2f(qf[i][0][e]), a1 = bits2f(qf[i][1][e]);
      qf[i][0][e] = f2bits(a0 * c + a1 * s);
      qf[i][1][e] = f2bits(a1 * c - a0 * s);
      float b0 = bits2f(kf[i][0][e]), b1 = bits2f(kf[i][1][e]);
      kf[i][0][e] = f2bits(b0 * c + b1 * s);
      kf[i][1][e] = f2bits(b1 * c - b0 * s);
    }
#undef CS_
  }

  // ---- V -> LDS transposed ----
  const short* vb = qb + 2048 + (long)lane * 3072;
#pragma unroll
  for (int w = 0; w < 8; w++) {
    short8 v8 = *(const short8*)(vb + w * 8);
#pragma unroll
    for (int e = 0; e < 8; e++) vt[w * 8 + e][lane] = v8[e];
  }
  __syncthreads();

  // ---- S = Q.K^T ----
  floatx4 sc[4][4];
#pragma unroll
  for (int mi = 0; mi < 4; mi++)
#pragma unroll
    for (int ni = 0; ni < 4; ni++) {
      sc[mi][ni] = (floatx4){0.f, 0.f, 0.f, 0.f};
      sc[mi][ni] = __builtin_amdgcn_mfma_f32_16x16x32_bf16(qf[mi][0], kf[ni][0], sc[mi][ni], 0, 0, 0);
      sc[mi][ni] = __builtin_amdgcn_mfma_f32_16x16x32_bf16(qf[mi][1], kf[ni][1], sc[mi][ni], 0, 0, 0);
    }

  // ---- softmax ----
  float is_[4][4];
#pragma unroll
  for (int mi = 0; mi < 4; mi++)
#pragma unroll
    for (int r = 0; r < 4; r++) {
      float mx = fmaxf(fmaxf(sc[mi][0][r], sc[mi][1][r]), fmaxf(sc[mi][2][r], sc[mi][3][r]));
      mx = fmaxf(mx, __shfl_xor(mx, 1));
      mx = fmaxf(mx, __shfl_xor(mx, 2));
      mx = fmaxf(mx, __shfl_xor(mx, 4));
      mx = fmaxf(mx, __shfl_xor(mx, 8));
      float sm = 0.f;
#pragma unroll
      for (int ni = 0; ni < 4; ni++) {
        float e_ = __expf((sc[mi][ni][r] - mx) * 0.125f);
        sc[mi][ni][r] = e_;
        sm += e_;
      }
      sm += __shfl_xor(sm, 1);
      sm += __shfl_xor(sm, 2);
      sm += __shfl_xor(sm, 4);
      sm += __shfl_xor(sm, 8);
      is_[mi][r] = 1.0f / sm;
    }

  // ---- P -> LDS bf16 ----
#pragma unroll
  for (int mi = 0; mi < 4; mi++)
#pragma unroll
    for (int ni = 0; ni < 4; ni++)
#pragma unroll
      for (int r = 0; r < 4; r++)
        ps[mi * 16 + quad * 4 + r][ni * 16 + frow] = f2bits(sc[mi][ni][r] * is_[mi][r]);
  __syncthreads();

  // ---- P, V^T fragments ----
  short8 pf[4][2], vf[4][2];
#pragma unroll
  for (int i = 0; i < 4; i++)
#pragma unroll
    for (int ks = 0; ks < 2; ks++) {
      const short* pp = &ps[frow + 16 * i][quad * 8 + 32 * ks];
      s16x4 p0 = *(const s16x4*)pp, p1 = *(const s16x4*)(pp + 4);
      const short* vp = &vt[frow + 16 * i][quad * 8 + 32 * ks];
      s16x4 v0 = *(const s16x4*)vp, v1 = *(const s16x4*)(vp + 4);
#pragma unroll
      for (int e = 0; e < 4; e++) {
        pf[i][ks][e] = p0[e]; pf[i][ks][e + 4] = p1[e];
        vf[i][ks][e] = v0[e]; vf[i][ks][e + 4] = v1[e];
      }
    }

  // ---- Y = P.V ----
  floatx4 oc[4][4];
#pragma unroll
  for (int mi = 0; mi < 4; mi++)
#pragma unroll
    for (int ni = 0; ni < 4; ni++) {
      oc[mi][ni] = (floatx4){0.f, 0.f, 0.f, 0.f};
      oc[mi][ni] = __builtin_amdgcn_mfma_f32_16x16x32_bf16(pf[mi][0], vf[ni][0], oc[mi][ni], 0, 0, 0);
      oc[mi][ni] = __builtin_amdgcn_mfma_f32_16x16x32_bf16(pf[mi][1], vf[ni][1], oc[mi][ni], 0, 0, 0);
    }

  // ---- Y -> LDS -> coalesced global store ----
  __syncthreads();
#pragma unroll
  for (int mi = 0; mi < 4; mi++)
#pragma unroll
    for (int ni = 0; ni < 4; ni++)
#pragma unroll
      for (int r = 0; r < 4; r++)
        ps[mi * 16 + quad * 4 + r][ni * 16 + frow] = f2bits(oc[mi][ni][r]);
  __syncthreads();

  short* dst = y + (rowbase + lane) * 1024 + h * 64;
#pragma unroll
  for (int w = 0; w < 8; w++) {
    const short* rp = &ps[lane][w * 8];
    s16x4 o0 = *(const s16x4*)rp, o1 = *(const s16x4*)(rp + 4);
    short8 o8;
#pragma unroll
    for (int e = 0; e < 4; e++) { o8[e] = o0[e]; o8[e + 4] = o1[e]; }
    *(short8*)(dst + w * 8) = o8;
  }
}

// ---------------------------------------------------------------------------
extern "C" void kernel_launch(void* const* d_in, const int* in_sizes, int n_in,
                              void* d_out, int out_size, void* d_ws, size_t ws_size,
                              hipStream_t stream) {
  (void)in_sizes; (void)n_in; (void)out_size; (void)ws_size;
  const float* x      = (const float*)d_in[0];  // f32 (4,4096,1024)
  const float* w_attn = (const float*)d_in[1];  // f32 (3072,1024)
  const float* w_proj = (const float*)d_in[2];  // f32 (1024,1024)
  float* out = (float*)d_out;                   // f32 (4,4096,1024)

  // ws: qkv 96 MiB | yb 32 MiB.  wab overlaps yb (dead before attn writes yb);
  // wpb overlaps qkv (written after attn reads qkv).
  // d_out scratch: xb (bf16 x, 32 MiB) + rope table (16 KiB at +32 MiB);
  // both dead before gemm2 overwrites all of out.
  short* qkv = (short*)d_ws;
  short* yb  = qkv + (size_t)16384 * 3072;
  short* wab = yb;
  short* wpb = qkv;
  short* xb  = (short*)d_out;
  float* tab = (float*)((char*)d_out + (size_t)32 * 1024 * 1024);

  cvt_bf16<<<dim3(2048), 256, 0, stream>>>(x,      xb,  (long)16384 * 1024 / 8);
  cvt_bf16<<<dim3(1024), 256, 0, stream>>>(w_attn, wab, (long)3072 * 1024 / 8);
  rope_table<<<dim3(8), 256, 0, stream>>>(tab);
  // qkv = x @ w_attn^T   (16384x3072x1024): grid 64x12 = 768 blocks
  gemm256<false><<<dim3(768), 512, 0, stream>>>(xb, wab, qkv, 16384, 3072, 1024);
  // chunked MFMA attention -> y (bf16)
  attn_mfma<<<dim3(16, 64, 4), 64, 0, stream>>>(qkv, yb, tab);
  cvt_bf16<<<dim3(512), 256, 0, stream>>>(w_proj, wpb, (long)1024 * 1024 / 8);
  // out = y @ w_proj^T   (16384x1024x1024): grid 64x4 = 256 blocks, f32 out
  gemm256<true><<<dim3(256), 512, 0, stream>>>(yb, wpb, out, 16384, 1024, 1024);
}

// Round 10
// 300.836 us; speedup vs baseline: 4.2233x; 1.0350x over previous
//
#include <hip/hip_runtime.h>
#include <math.h>

typedef __attribute__((ext_vector_type(8))) short short8;
typedef __attribute__((ext_vector_type(4))) short s16x4;
typedef __attribute__((ext_vector_type(4))) float floatx4;

__device__ __forceinline__ float bits2f(short u) {
  unsigned int x = ((unsigned int)(unsigned short)u) << 16;
  return __builtin_bit_cast(float, x);
}
__device__ __forceinline__ short f2bits(float f) {
  unsigned int x = __builtin_bit_cast(unsigned int, f);
  x += 0x7FFFu + ((x >> 16) & 1u);   // RNE
  return (short)(x >> 16);
}

__device__ __forceinline__ void gload_lds16(const short* g, short* l) {
  __builtin_amdgcn_global_load_lds((const __attribute__((address_space(1))) void*)g,
                                   (__attribute__((address_space(3))) void*)l, 16, 0, 0);
}

// ---------------------------------------------------------------------------
// f32 -> bf16 (RNE), 8 elems/thread, grid-stride. n8 = n_elems/8.
// ---------------------------------------------------------------------------
__global__ __launch_bounds__(256) void cvt_bf16(const float* __restrict__ in,
                                                short* __restrict__ out, long n8) {
  long i = (long)blockIdx.x * 256 + threadIdx.x;
  const long stride = (long)gridDim.x * 256;
  for (; i < n8; i += stride) {
    const floatx4* p = (const floatx4*)(in + i * 8);
    floatx4 v0 = p[0], v1 = p[1];
    short8 o;
#pragma unroll
    for (int e = 0; e < 4; e++) { o[e] = f2bits(v0[e]); o[e + 4] = f2bits(v1[e]); }
    *(short8*)(out + i * 8) = o;
  }
}

// ---------------------------------------------------------------------------
// rope table: tab[t][j] = {cos(t*inv_j), sin(t*inv_j)} interleaved f32.
// ---------------------------------------------------------------------------
__global__ __launch_bounds__(256) void rope_table(float* __restrict__ tab) {
  int i = blockIdx.x * 256 + threadIdx.x;   // 0..2047
  if (i >= 64 * 32) return;
  int t = i >> 5, j = i & 31;
  float inv = exp2f(-(float)j * 0.41524101186092030f);  // 10000^(-j/32)
  float ang = (float)t * inv;
  tab[i * 2]     = cosf(ang);
  tab[i * 2 + 1] = sinf(ang);
}

// ---------------------------------------------------------------------------
// C[m][n] = sum_k A[m][k]*B[n][k], bf16 in, fp32 acc. 256x256 tile, BK=32,
// 8 waves (2M x 4N, wave tile 128x64), ring-4 LDS pipeline (4 x 32KB slots),
// counted vmcnt (never 0 in main loop), raw s_barrier, setprio on MFMA.
// Bank swizzle (rule 21 both-sides): LDS dest stays linear for
// global_load_lds; the global SOURCE k-chunk is permuted slot^((row>>1)&3)
// and the ds_read applies the same involution.  [R7: conflicts 9.4M -> 0]
// Requires M%256==0, N%256==0, K%32==0, K>=128, gridDim.x%8==0.
// ---------------------------------------------------------------------------
template <bool COUT_F32>
__global__ __launch_bounds__(512, 2) void gemm256(const short* __restrict__ A,
                                                  const short* __restrict__ B,
                                                  void* __restrict__ C,
                                                  int M, int N, int K) {
  (void)M;
  __shared__ __attribute__((aligned(16))) short lds[65536];  // 4 slots x (A 16KB | B 16KB)

  const int t    = threadIdx.x;          // 0..511
  const int lane = t & 63;
  const int wave = t >> 6;               // 0..7
  const int wm   = wave >> 2;            // 0..1
  const int wn   = wave & 3;             // 0..3
  const int frow = lane & 15;
  const int quad = lane >> 4;

  // bijective XCD-aware swizzle (gridDim.x % 8 == 0)
  const int nwg = gridDim.x;
  const int cpx = nwg >> 3;
  const int bid = blockIdx.x;
  const int swz = (bid & 7) * cpx + (bid >> 3);
  const int nbx = N >> 8;
  const int bx  = swz % nbx;
  const int by  = swz / nbx;
  const long m0 = (long)by * 256;
  const long n0 = (long)bx * 256;

  const int NT = K >> 5;                 // K-tiles of 32

  // staging: thread t -> LDS (row=t>>2, slot=t&3) linear; global k-chunk = slot^((row>>1)&3)
  const int  srow  = t >> 2;             // 0..127
  const int  scol  = ((t & 3) ^ ((srow >> 1) & 3)) * 8;   // pre-permuted source col
  const long aoff0 = (m0 + srow) * (long)K + scol;
  const long aoff1 = aoff0 + 128L * K;
  const long boff0 = (n0 + srow) * (long)K + scol;
  const long boff1 = boff0 + 128L * K;
  const int  t8    = t * 8;              // linear LDS dest (shorts)

  // fragment read: logical k-chunk quad lives at LDS slot quad^((frow>>1)&3)
  const int sw8 = (quad ^ ((frow >> 1) & 3)) * 8;

  floatx4 acc[8][4];
#pragma unroll
  for (int i = 0; i < 8; i++)
#pragma unroll
    for (int j = 0; j < 4; j++) acc[i][j] = (floatx4){0.f, 0.f, 0.f, 0.f};

  // prologue: stage tiles 0,1,2 into slots 0,1,2 (12 issues/thread)
  for (int p = 0; p < 3; ++p) {
    short* la = lds + p * 16384;
    const long kk = (long)p * 32;
    gload_lds16(A + aoff0 + kk, la + t8);
    gload_lds16(A + aoff1 + kk, la + t8 + 4096);
    gload_lds16(B + boff0 + kk, la + 8192 + t8);
    gload_lds16(B + boff1 + kk, la + 8192 + t8 + 4096);
  }

#define GSTEP(KT, VMSTR, DO_STAGE)                                                     \
  {                                                                                    \
    const int kt_ = (KT);                                                              \
    asm volatile("s_barrier" ::: "memory");  /* all waves done reading slot kt_-1 */   \
    if (DO_STAGE) {                                                                    \
      short* sa = lds + ((kt_ + 3) & 3) * 16384;                                       \
      const long kk = (long)(kt_ + 3) * 32;                                            \
      gload_lds16(A + aoff0 + kk, sa + t8);                                            \
      gload_lds16(A + aoff1 + kk, sa + t8 + 4096);                                     \
    }                                                                                  \
    asm volatile("s_waitcnt " VMSTR ::: "memory");  /* own share of tile kt_ landed */ \
    asm volatile("s_barrier" ::: "memory");         /* everyone's share landed */      \
    {                                                                                  \
      const short* la = lds + (kt_ & 3) * 16384;                                       \
      const short* lb = la + 8192;                                                     \
      short8 af[8], bf[4];                                                             \
      _Pragma("unroll")                                                                \
      for (int ni = 0; ni < 4; ni++)                                                   \
        bf[ni] = *(const short8*)&lb[(wn * 64 + ni * 16 + frow) * 32 + sw8];           \
      _Pragma("unroll")                                                                \
      for (int mi = 0; mi < 8; mi++)                                                   \
        af[mi] = *(const short8*)&la[(wm * 128 + mi * 16 + frow) * 32 + sw8];          \
      __builtin_amdgcn_s_setprio(1);                                                   \
      _Pragma("unroll")                                                                \
      for (int mi = 0; mi < 4; mi++)                                                   \
        _Pragma("unroll")                                                              \
        for (int ni = 0; ni < 4; ni++)                                                 \
          acc[mi][ni] =                                                                \
              __builtin_amdgcn_mfma_f32_16x16x32_bf16(af[mi], bf[ni], acc[mi][ni], 0, 0, 0); \
      __builtin_amdgcn_s_setprio(0);                                                   \
      if (DO_STAGE) {                                                                  \
        short* sb = lds + ((kt_ + 3) & 3) * 16384;                                     \
        const long kk = (long)(kt_ + 3) * 32;                                          \
        gload_lds16(B + boff0 + kk, sb + 8192 + t8);                                   \
        gload_lds16(B + boff1 + kk, sb + 8192 + t8 + 4096);                            \
      }                                                                                \
      __builtin_amdgcn_s_setprio(1);                                                   \
      _Pragma("unroll")                                                                \
      for (int mi = 4; mi < 8; mi++)                                                   \
        _Pragma("unroll")                                                              \
        for (int ni = 0; ni < 4; ni++)                                                 \
          acc[mi][ni] =                                                                \
              __builtin_amdgcn_mfma_f32_16x16x32_bf16(af[mi], bf[ni], acc[mi][ni], 0, 0, 0); \
      __builtin_amdgcn_s_setprio(0);                                                   \
    }                                                                                  \
  }

  // main loop: tiles kt+1,kt+2 fully in flight + stageA(kt+3) = 10 outstanding
  for (int kt = 0; kt <= NT - 4; ++kt) GSTEP(kt, "vmcnt(10)", true);
  GSTEP(NT - 3, "vmcnt(8)", false);
  GSTEP(NT - 2, "vmcnt(4)", false);
  GSTEP(NT - 1, "vmcnt(0)", false);
#undef GSTEP

  // epilogue: C/D layout col=lane&15, row=quad*4+r (verified convention)
  const long mrow0 = m0 + wm * 128;
  const long ncol0 = n0 + wn * 64;
#pragma unroll
  for (int mi = 0; mi < 8; mi++)
#pragma unroll
    for (int ni = 0; ni < 4; ni++) {
      long row0 = mrow0 + mi * 16 + quad * 4;
      long col  = ncol0 + ni * 16 + frow;
#pragma unroll
      for (int r = 0; r < 4; r++) {
        if constexpr (COUT_F32)
          ((float*)C)[(row0 + r) * (long)N + col] = acc[mi][ni][r];
        else
          ((short*)C)[(row0 + r) * (long)N + col] = f2bits(acc[mi][ni][r]);
      }
    }
}

// ---------------------------------------------------------------------------
// MFMA attention (1 wave per (head, chunk, batch)) — R3/R7 verified dataflow.
// Two 64x64x64 bt-GEMMs; wave-parallel softmax via shfl_xor in 16-lane
// groups. Single change vs R7: Y stores go DIRECT from the accumulator
// (register->global, per-lane own addresses, bijective — no LDS round trip,
// two fewer barriers). Mapping identical to the staged path by construction.
// ---------------------------------------------------------------------------
__global__ __launch_bounds__(64, 1) void attn_mfma(const short* __restrict__ qkv,
                                                   short* __restrict__ y,
                                                   const float* __restrict__ cstab) {
  const int lane = threadIdx.x;
  const int frow = lane & 15;
  const int quad = lane >> 4;
  const int h = blockIdx.x, chunk = blockIdx.y, b = blockIdx.z;
  const long rowbase = (long)b * 4096 + (long)chunk * 64;

  __shared__ __attribute__((aligned(16))) short vt[64][68];  // V^T: vt[d][j]
  __shared__ __attribute__((aligned(16))) short ps[64][68];  // P staging

  const short* qb = qkv + rowbase * 3072 + h * 64;

  // ---- Q,K fragments from global + in-register rope -> bf16 ----
  short8 qf[4][2], kf[4][2];
#pragma unroll
  for (int i = 0; i < 4; i++) {
    const short* rq = qb + (long)(16 * i + frow) * 3072 + quad * 8;
    qf[i][0] = *(const short8*)(rq);
    qf[i][1] = *(const short8*)(rq + 32);
    kf[i][0] = *(const short8*)(rq + 1024);
    kf[i][1] = *(const short8*)(rq + 1056);
    const floatx4* tp = (const floatx4*)(cstab + ((16 * i + frow) * 32 + quad * 8) * 2);
    floatx4 tv0 = tp[0], tv1 = tp[1], tv2 = tp[2], tv3 = tp[3];
#define CS_(k) ((k) < 4 ? tv0[(k) & 3] : (k) < 8 ? tv1[(k) & 3] : (k) < 12 ? tv2[(k) & 3] : tv3[(k) & 3])
#pragma unroll
    for (int e = 0; e < 8; e++) {
      float c = CS_(2 * e), s = CS_(2 * e + 1);
      float a0 = bits2f(qf[i][0][e]), a1 = bits2f(qf[i][1][e]);
      qf[i][0][e] = f2bits(a0 * c + a1 * s);
      qf[i][1][e] = f2bits(a1 * c - a0 * s);
      float b0 = bits2f(kf[i][0][e]), b1 = bits2f(kf[i][1][e]);
      kf[i][0][e] = f2bits(b0 * c + b1 * s);
      kf[i][1][e] = f2bits(b1 * c - b0 * s);
    }
#undef CS_
  }

  // ---- V -> LDS transposed ----
  const short* vb = qb + 2048 + (long)lane * 3072;
#pragma unroll
  for (int w = 0; w < 8; w++) {
    short8 v8 = *(const short8*)(vb + w * 8);
#pragma unroll
    for (int e = 0; e < 8; e++) vt[w * 8 + e][lane] = v8[e];
  }
  __syncthreads();

  // ---- S = Q.K^T ----
  floatx4 sc[4][4];
#pragma unroll
  for (int mi = 0; mi < 4; mi++)
#pragma unroll
    for (int ni = 0; ni < 4; ni++) {
      sc[mi][ni] = (floatx4){0.f, 0.f, 0.f, 0.f};
      sc[mi][ni] = __builtin_amdgcn_mfma_f32_16x16x32_bf16(qf[mi][0], kf[ni][0], sc[mi][ni], 0, 0, 0);
      sc[mi][ni] = __builtin_amdgcn_mfma_f32_16x16x32_bf16(qf[mi][1], kf[ni][1], sc[mi][ni], 0, 0, 0);
    }

  // ---- softmax ----
  float is_[4][4];
#pragma unroll
  for (int mi = 0; mi < 4; mi++)
#pragma unroll
    for (int r = 0; r < 4; r++) {
      float mx = fmaxf(fmaxf(sc[mi][0][r], sc[mi][1][r]), fmaxf(sc[mi][2][r], sc[mi][3][r]));
      mx = fmaxf(mx, __shfl_xor(mx, 1));
      mx = fmaxf(mx, __shfl_xor(mx, 2));
      mx = fmaxf(mx, __shfl_xor(mx, 4));
      mx = fmaxf(mx, __shfl_xor(mx, 8));
      float sm = 0.f;
#pragma unroll
      for (int ni = 0; ni < 4; ni++) {
        float e_ = __expf((sc[mi][ni][r] - mx) * 0.125f);
        sc[mi][ni][r] = e_;
        sm += e_;
      }
      sm += __shfl_xor(sm, 1);
      sm += __shfl_xor(sm, 2);
      sm += __shfl_xor(sm, 4);
      sm += __shfl_xor(sm, 8);
      is_[mi][r] = 1.0f / sm;
    }

  // ---- P -> LDS bf16 ----
#pragma unroll
  for (int mi = 0; mi < 4; mi++)
#pragma unroll
    for (int ni = 0; ni < 4; ni++)
#pragma unroll
      for (int r = 0; r < 4; r++)
        ps[mi * 16 + quad * 4 + r][ni * 16 + frow] = f2bits(sc[mi][ni][r] * is_[mi][r]);
  __syncthreads();

  // ---- P, V^T fragments ----
  short8 pf[4][2], vf[4][2];
#pragma unroll
  for (int i = 0; i < 4; i++)
#pragma unroll
    for (int ks = 0; ks < 2; ks++) {
      const short* pp = &ps[frow + 16 * i][quad * 8 + 32 * ks];
      s16x4 p0 = *(const s16x4*)pp, p1 = *(const s16x4*)(pp + 4);
      const short* vp = &vt[frow + 16 * i][quad * 8 + 32 * ks];
      s16x4 v0 = *(const s16x4*)vp, v1 = *(const s16x4*)(vp + 4);
#pragma unroll
      for (int e = 0; e < 4; e++) {
        pf[i][ks][e] = p0[e]; pf[i][ks][e + 4] = p1[e];
        vf[i][ks][e] = v0[e]; vf[i][ks][e + 4] = v1[e];
      }
    }

  // ---- Y = P.V ----
  floatx4 oc[4][4];
#pragma unroll
  for (int mi = 0; mi < 4; mi++)
#pragma unroll
    for (int ni = 0; ni < 4; ni++) {
      oc[mi][ni] = (floatx4){0.f, 0.f, 0.f, 0.f};
      oc[mi][ni] = __builtin_amdgcn_mfma_f32_16x16x32_bf16(pf[mi][0], vf[ni][0], oc[mi][ni], 0, 0, 0);
      oc[mi][ni] = __builtin_amdgcn_mfma_f32_16x16x32_bf16(pf[mi][1], vf[ni][1], oc[mi][ni], 0, 0, 0);
    }

  // ---- direct store from accumulator (q = 16mi+4quad+r, d = 16ni+frow) ----
#pragma unroll
  for (int mi = 0; mi < 4; mi++)
#pragma unroll
    for (int ni = 0; ni < 4; ni++)
#pragma unroll
      for (int r = 0; r < 4; r++)
        y[(rowbase + mi * 16 + quad * 4 + r) * 1024 + h * 64 + ni * 16 + frow] =
            f2bits(oc[mi][ni][r]);
}

// ---------------------------------------------------------------------------
extern "C" void kernel_launch(void* const* d_in, const int* in_sizes, int n_in,
                              void* d_out, int out_size, void* d_ws, size_t ws_size,
                              hipStream_t stream) {
  (void)in_sizes; (void)n_in; (void)out_size; (void)ws_size;
  const float* x      = (const float*)d_in[0];  // f32 (4,4096,1024)
  const float* w_attn = (const float*)d_in[1];  // f32 (3072,1024)
  const float* w_proj = (const float*)d_in[2];  // f32 (1024,1024)
  float* out = (float*)d_out;                   // f32 (4,4096,1024)

  // ws: qkv 96 MiB | yb 32 MiB.  wab overlaps yb (dead before attn writes yb);
  // wpb overlaps qkv (written after attn reads qkv).
  // d_out scratch: xb (bf16 x, 32 MiB) + rope table (16 KiB at +32 MiB);
  // both dead before gemm2 overwrites all of out.
  short* qkv = (short*)d_ws;
  short* yb  = qkv + (size_t)16384 * 3072;
  short* wab = yb;
  short* wpb = qkv;
  short* xb  = (short*)d_out;
  float* tab = (float*)((char*)d_out + (size_t)32 * 1024 * 1024);

  cvt_bf16<<<dim3(2048), 256, 0, stream>>>(x,      xb,  (long)16384 * 1024 / 8);
  cvt_bf16<<<dim3(1024), 256, 0, stream>>>(w_attn, wab, (long)3072 * 1024 / 8);
  rope_table<<<dim3(8), 256, 0, stream>>>(tab);
  // qkv = x @ w_attn^T   (16384x3072x1024): grid 768 blocks
  gemm256<false><<<dim3(768), 512, 0, stream>>>(xb, wab, qkv, 16384, 3072, 1024);
  // chunked MFMA attention -> y (bf16)
  attn_mfma<<<dim3(16, 64, 4), 64, 0, stream>>>(qkv, yb, tab);
  cvt_bf16<<<dim3(512), 256, 0, stream>>>(w_proj, wpb, (long)1024 * 1024 / 8);
  // out = y @ w_proj^T   (16384x1024x1024): grid 256 blocks, f32 out
  gemm256<true><<<dim3(256), 512, 0, stream>>>(yb, wpb, out, 16384, 1024, 1024);
}